// Round 1
// baseline (11834.450 us; speedup 1.0000x reference)
//
#include <hip/hip_runtime.h>

typedef unsigned int u32;
typedef unsigned short u16;
typedef __attribute__((ext_vector_type(8))) short short8;
typedef __attribute__((ext_vector_type(4))) float floatx4;

#define TT 1024
#define KX 64        // padded x-input dim (43 -> 64)
#define KTOT 320     // KX + H
#define XH_S 328     // LDS row stride (ushorts) for [x|h] tile, padded for banks
#define BIN_OFF 6553600
#define ACT_OFF 7864320

__device__ __forceinline__ u16 f2b(float f) {
  u32 u = __builtin_bit_cast(u32, f);
  u += 0x7fffu + ((u >> 16) & 1u);
  return (u16)(u >> 16);
}
__device__ __forceinline__ float sigmf(float x) { return 1.0f / (1.0f + __expf(-x)); }
__device__ __forceinline__ float tanhfast(float x) {
  x = fminf(x, 15.0f);                      // avoid inf/inf
  float e = __expf(2.0f * x);
  return (e - 1.0f) / (e + 1.0f);
}

// ---------------- weight/input prep ----------------

// Wcat[n][k]: k<43 -> W_ih[n][k]; 64<=k<320 -> W_hh[n][k-64]; else 0.  grid 1024 x 320
__global__ void k_prep_wcat(const float* __restrict__ wih, const float* __restrict__ whh,
                            u16* __restrict__ wcat) {
  int nrow = blockIdx.x, k = threadIdx.x;
  float v = 0.f;
  if (k < 43) v = wih[nrow * 43 + k];
  else if (k >= 64) v = whh[nrow * 256 + (k - 64)];
  wcat[nrow * 320 + k] = f2b(v);
}
// bias = b_ih + b_hh.  grid 4 x 256
__global__ void k_prep_bias(const float* __restrict__ a, const float* __restrict__ b,
                            float* __restrict__ o) {
  int i = blockIdx.x * 256 + threadIdx.x;
  o[i] = a[i] + b[i];
}
// W_afc1 (256x256) and W_aout padded to 16x256.  grid 272 x 256
__global__ void k_prep_afc(const float* __restrict__ wafc1, const float* __restrict__ waout,
                           u16* __restrict__ ob1, u16* __restrict__ ob2) {
  int r = blockIdx.x, k = threadIdx.x;
  if (r < 256) ob1[r * 256 + k] = f2b(wafc1[r * 256 + k]);
  else {
    int y = r - 256;
    ob2[y * 256 + k] = f2b(y < 8 ? waout[y * 256 + k] : 0.f);
  }
}
// Wcb[64][288]: rows 0..49 W_cont, 50..59 W_bin, k<264 real, else 0.  grid 64 x 288
__global__ void k_prep_wcb(const float* __restrict__ wcont, const float* __restrict__ wbin,
                           u16* __restrict__ o) {
  int nrow = blockIdx.x, k = threadIdx.x;
  float v = 0.f;
  if (k < 264) {
    if (nrow < 50) v = wcont[nrow * 264 + k];
    else if (nrow < 60) v = wbin[(nrow - 50) * 264 + k];
  }
  o[nrow * 288 + k] = f2b(v);
}
// xin[b][t][64] bf16: d<35 -> x[b][t][d]; 35<=d<43 -> x[b][t-1][d] (0 at t=0); else 0.
// grid 32768 x 256
__global__ void k_prep_xin(const float* __restrict__ x, u16* __restrict__ xin) {
  size_t idx = (size_t)blockIdx.x * 256 + threadIdx.x;
  size_t bt = idx >> 6;
  int d = (int)(idx & 63);
  int t = (int)(bt & 1023);
  float v = 0.f;
  if (d < 35) v = x[bt * 43 + d];
  else if (d < 43 && t > 0) v = x[(bt - 1) * 43 + d];
  xin[idx] = f2b(v);
}

// ---------------- LSTM scan ----------------
// 8 WGs x 1024 threads (16 waves). WG g owns batch rows [16g,16g+16).
// Per step: gates(16x1024) = [x_t|h] (16x320) @ Wcat^T via mfma 16x16x32 bf16.
// Wave w owns gate columns {i,f,g,o} x hd in [16w,16w+16) -> elementwise LSTM fully
// in registers (C-layout aligned across the 4 gates), no gate exchange needed.
__global__ __launch_bounds__(1024, 4)
void k_scan(const u16* __restrict__ wcat, const u16* __restrict__ xin,
            const float* __restrict__ bias, u16* __restrict__ hs) {
  __shared__ u16 xh[16 * XH_S];      // [m=16][k=328] bf16, cols 0..63 = x_t, 64..319 = h
  __shared__ float sbias[1024];
  const int tid = threadIdx.x;
  const int wave = tid >> 6;
  const int lane = tid & 63;
  const int l15 = lane & 15;
  const int kq = lane >> 4;
  const int b0 = blockIdx.x * 16;

  sbias[tid] = bias[tid];
  for (int i = tid; i < 16 * XH_S; i += 1024) xh[i] = 0;
  __syncthreads();
  if (tid < 512) {  // load x_0 (16 rows x 64 bf16 = 512 dwords)
    const int r = tid >> 5, c = tid & 31;
    *(u32*)&xh[r * XH_S + c * 2] =
        *(const u32*)(xin + (size_t)(b0 + r) * TT * KX + c * 2);
  }
  size_t boff[4];
  float bias_r[4];
#pragma unroll
  for (int g = 0; g < 4; ++g) {
    int n = g * 256 + wave * 16 + l15;     // gate g, hidden col (wave*16+l15)
    boff[g] = (size_t)n * KTOT + (size_t)kq * 8;
    bias_r[g] = sbias[n];
  }
  __syncthreads();

  float c_st[4] = {0.f, 0.f, 0.f, 0.f};    // c for rows m = kq*4+rr at col hd
  const int hd = wave * 16 + l15;
  const int ard = l15 * XH_S + kq * 8;

  for (int t = 0; t < TT; ++t) {
    floatx4 acc[4];
#pragma unroll
    for (int g = 0; g < 4; ++g) acc[g] = (floatx4){0.f, 0.f, 0.f, 0.f};
#pragma unroll
    for (int kt = 0; kt < 10; ++kt) {
      short8 afr = *(const short8*)&xh[ard + kt * 32];
#pragma unroll
      for (int g = 0; g < 4; ++g) {
        short8 bfr = *(const short8*)(wcat + boff[g] + kt * 32);
        acc[g] = __builtin_amdgcn_mfma_f32_16x16x32_bf16(afr, bfr, acc[g], 0, 0, 0);
      }
    }
    __syncthreads();                       // all xh reads complete
    u32 xv = 0;
    if (tid < 512 && t + 1 < TT) {         // prefetch x_{t+1} (overlaps elementwise)
      const int r = tid >> 5, c = tid & 31;
      xv = *(const u32*)(xin + ((size_t)(b0 + r) * TT + (size_t)(t + 1)) * KX + c * 2);
    }
#pragma unroll
    for (int rr = 0; rr < 4; ++rr) {       // C-layout: row m = kq*4+rr, col = hd
      float iv = sigmf(acc[0][rr] + bias_r[0]);
      float fv = sigmf(acc[1][rr] + bias_r[1]);
      float gv = tanhfast(acc[2][rr] + bias_r[2]);
      float ov = sigmf(acc[3][rr] + bias_r[3]);
      float cc = fv * c_st[rr] + iv * gv;
      c_st[rr] = cc;
      float h = ov * tanhfast(cc);
      u16 hb = f2b(h);
      int m = kq * 4 + rr;
      xh[m * XH_S + KX + hd] = hb;
      hs[((size_t)(b0 + m) * TT + (size_t)t) * 256 + hd] = hb;
    }
    if (tid < 512 && t + 1 < TT) {
      const int r = tid >> 5, c = tid & 31;
      *(u32*)&xh[r * XH_S + c * 2] = xv;
    }
    __syncthreads();
  }
}

// ---------------- post: act = relu(hs@W_afc1^T+b1)@W_aout^T+b2 ----------------
// 8192 blocks x 256 threads; block handles 16 (b,t) rows.
__global__ __launch_bounds__(256, 2)
void k_act(const u16* __restrict__ hs, const u16* __restrict__ wafc1,
           const u16* __restrict__ waout, const float* __restrict__ b_afc1,
           const float* __restrict__ b_aout, float* __restrict__ act) {
  __shared__ u16 a_sh[16 * 264];
  __shared__ u16 z_sh[16 * 264];
  __shared__ float sb1[256];
  const int tid = threadIdx.x;
  const int wave = tid >> 6, lane = tid & 63;
  const int l15 = lane & 15, kq = lane >> 4;
  const size_t bt0 = (size_t)blockIdx.x * 16;
  sb1[tid] = b_afc1[tid];
#pragma unroll
  for (int i = 0; i < 2; ++i) {
    int chunk = i * 256 + tid;
    int row = chunk >> 5, c = chunk & 31;
    *(uint4*)&a_sh[row * 264 + c * 8] = *(const uint4*)(hs + (bt0 + row) * 256 + c * 8);
  }
  __syncthreads();
  floatx4 acc[4];
#pragma unroll
  for (int nt = 0; nt < 4; ++nt) acc[nt] = (floatx4){0.f, 0.f, 0.f, 0.f};
#pragma unroll
  for (int kt = 0; kt < 8; ++kt) {
    short8 a = *(const short8*)&a_sh[l15 * 264 + kt * 32 + kq * 8];
#pragma unroll
    for (int nt = 0; nt < 4; ++nt) {
      int n = wave * 64 + nt * 16 + l15;
      short8 b = *(const short8*)(wafc1 + n * 256 + kt * 32 + kq * 8);
      acc[nt] = __builtin_amdgcn_mfma_f32_16x16x32_bf16(a, b, acc[nt], 0, 0, 0);
    }
  }
#pragma unroll
  for (int nt = 0; nt < 4; ++nt) {
    int n = wave * 64 + nt * 16 + l15;
    float bb = sb1[n];
#pragma unroll
    for (int r = 0; r < 4; ++r) {
      float v = acc[nt][r] + bb;
      v = v > 0.f ? v : 0.f;
      z_sh[(kq * 4 + r) * 264 + n] = f2b(v);
    }
  }
  __syncthreads();
  if (wave == 0) {
    floatx4 a2 = (floatx4){0.f, 0.f, 0.f, 0.f};
#pragma unroll
    for (int kt = 0; kt < 8; ++kt) {
      short8 a = *(const short8*)&z_sh[l15 * 264 + kt * 32 + kq * 8];
      short8 b = *(const short8*)(waout + l15 * 256 + kt * 32 + kq * 8);
      a2 = __builtin_amdgcn_mfma_f32_16x16x32_bf16(a, b, a2, 0, 0, 0);
    }
    if (l15 < 8) {
      float bb = b_aout[l15];
#pragma unroll
      for (int r = 0; r < 4; ++r)
        act[(bt0 + (size_t)(kq * 4 + r)) * 8 + l15] = a2[r] + bb;
    }
  }
}

// ---------------- post: cont/bin heads ----------------
// pred = [hs|cur] (K=264 pad 288) @ Wcb^T (N=64: 50 cont + 10 bin + pad).
__global__ __launch_bounds__(256, 2)
void k_cb(const u16* __restrict__ hs, const float* __restrict__ x,
          const u16* __restrict__ wcb, const float* __restrict__ b_cont,
          const float* __restrict__ b_bin, float* __restrict__ dout) {
  __shared__ u16 a_sh[16 * 296];
  const int tid = threadIdx.x;
  const int wave = tid >> 6, lane = tid & 63;
  const int l15 = lane & 15, kq = lane >> 4;
  const size_t bt0 = (size_t)blockIdx.x * 16;
#pragma unroll
  for (int i = 0; i < 2; ++i) {
    int chunk = i * 256 + tid;
    int row = chunk >> 5, c = chunk & 31;
    *(uint4*)&a_sh[row * 296 + c * 8] = *(const uint4*)(hs + (bt0 + row) * 256 + c * 8);
  }
  if (tid < 128) {  // cur = x[b][t][35..42]
    int m = tid >> 3, j = tid & 7;
    a_sh[m * 296 + 256 + j] = f2b(x[(bt0 + m) * 43 + 35 + j]);
  }
  for (int i = tid; i < 384; i += 256) {  // zero pad cols 264..287
    int m = i / 24, jj = i % 24;
    a_sh[m * 296 + 264 + jj] = 0;
  }
  __syncthreads();
  const int n = wave * 16 + l15;
  floatx4 acc = (floatx4){0.f, 0.f, 0.f, 0.f};
#pragma unroll
  for (int kt = 0; kt < 9; ++kt) {
    short8 a = *(const short8*)&a_sh[l15 * 296 + kt * 32 + kq * 8];
    short8 b = *(const short8*)(wcb + n * 288 + kt * 32 + kq * 8);
    acc = __builtin_amdgcn_mfma_f32_16x16x32_bf16(a, b, acc, 0, 0, 0);
  }
  if (n < 50) {
    float bb = b_cont[n];
#pragma unroll
    for (int r = 0; r < 4; ++r)
      dout[(bt0 + (size_t)(kq * 4 + r)) * 50 + n] = acc[r] + bb;
  } else if (n < 60) {
    float bb = b_bin[n - 50];
#pragma unroll
    for (int r = 0; r < 4; ++r)
      dout[BIN_OFF + (bt0 + (size_t)(kq * 4 + r)) * 10 + (n - 50)] = sigmf(acc[r] + bb);
  }
}

// ---------------- launch ----------------
extern "C" void kernel_launch(void* const* d_in, const int* in_sizes, int n_in,
                              void* d_out, int out_size, void* d_ws, size_t ws_size,
                              hipStream_t stream) {
  const float* x      = (const float*)d_in[0];
  const float* W_ih   = (const float*)d_in[1];
  const float* W_hh   = (const float*)d_in[2];
  const float* b_ih   = (const float*)d_in[3];
  const float* b_hh   = (const float*)d_in[4];
  const float* W_afc1 = (const float*)d_in[5];
  const float* b_afc1 = (const float*)d_in[6];
  const float* W_aout = (const float*)d_in[7];
  const float* b_aout = (const float*)d_in[8];
  const float* W_cont = (const float*)d_in[9];
  const float* b_cont = (const float*)d_in[10];
  const float* b_bin  = (const float*)d_in[12];
  const float* W_bin  = (const float*)d_in[11];

  char* ws = (char*)d_ws;
  u16*   wcat   = (u16*)(ws);                    // 655,360 B
  float* bias   = (float*)(ws + 655360);         //   4,096 B
  u16*   wafc1b = (u16*)(ws + 659456);           // 131,072 B
  u16*   waoutb = (u16*)(ws + 790528);           //   8,192 B
  u16*   wcbb   = (u16*)(ws + 798720);           //  36,864 B
  u16*   xin    = (u16*)(ws + 835584);           // 16,777,216 B
  u16*   hs     = (u16*)(ws + 17612800);         // 67,108,864 B  (total ~84.7 MB)
  float* outf   = (float*)d_out;

  hipLaunchKernelGGL(k_prep_wcat, dim3(1024), dim3(320), 0, stream, W_ih, W_hh, wcat);
  hipLaunchKernelGGL(k_prep_bias, dim3(4), dim3(256), 0, stream, b_ih, b_hh, bias);
  hipLaunchKernelGGL(k_prep_afc, dim3(272), dim3(256), 0, stream, W_afc1, W_aout, wafc1b, waoutb);
  hipLaunchKernelGGL(k_prep_wcb, dim3(64), dim3(288), 0, stream, W_cont, W_bin, wcbb);
  hipLaunchKernelGGL(k_prep_xin, dim3(32768), dim3(256), 0, stream, x, xin);
  hipLaunchKernelGGL(k_scan, dim3(8), dim3(1024), 0, stream, wcat, xin, bias, hs);
  hipLaunchKernelGGL(k_act, dim3(8192), dim3(256), 0, stream, hs, wafc1b, waoutb, b_afc1, b_aout, outf + ACT_OFF);
  hipLaunchKernelGGL(k_cb, dim3(8192), dim3(256), 0, stream, hs, x, wcbb, b_cont, b_bin, outf);
}